// Round 7
// baseline (218.184 us; speedup 1.0000x reference)
//
#include <hip/hip_runtime.h>
#include <hip/hip_bf16.h>
#include <hip/hip_cooperative_groups.h>

namespace cg = cooperative_groups;

// NT-Xent loss, N=4096, D=256, fp32 inputs, fp32 scalar output.
// loss = mean_i [ log( sum_{j != i} exp(2*cos(zn_i, zn_j)) ) - 2*cos(zn_i, zn_pair(i)) ]
//
// v7 = v6 (single cooperative kernel) + synchronous-error fallback to the
// proven v5 3-kernel path. r6 "container failed twice" is ambiguous between
// spurious infra (r3 precedent) and a cooperative co-residency deadlock; the
// fallback converts any clean launch error into a working run, and a repeat
// hard-failure would conclusively indict grid.sync co-residency.
//
// Fused kernel (512 blocks x 256 thr, 2/CU):
//   phase1: normalize 16 rows/block -> bf16 zn, invn, zero rowsum | grid.sync
//   phase2: circulant symmetric Gram exp-rowsums (counted-vmcnt rolling DMA
//           pipeline, 0 bank conflicts)                           | grid.sync
//   phase3: per-row contrib + block reduce -> atomicAdd(out)

#define NROWS 8192
#define NHALF 4096
#define DDIM  256
#define NBLK  512

typedef __bf16 bf16;
typedef __bf16 bf16x4 __attribute__((ext_vector_type(4)));
typedef __bf16 bf16x8 __attribute__((ext_vector_type(8)));
typedef float  f32x4  __attribute__((ext_vector_type(4)));

__constant__ const float kTwoLog2e = 2.8853900817779268f;  // 2*log2(e): exp(2x)=exp2(kTwoLog2e*x)
__constant__ const float kLn2      = 0.6931471805599453f;

__device__ __forceinline__ const float* zrow(const float* z1, const float* z2, int r) {
  return (r < NHALF) ? (z1 + (size_t)r * DDIM) : (z2 + (size_t)(r - NHALF) * DDIM);
}

typedef const __attribute__((address_space(1))) unsigned int* as1_u32p;
typedef __attribute__((address_space(3))) unsigned int* as3_u32p;

__device__ __forceinline__ void load_lds16(const void* g, void* l) {
  __builtin_amdgcn_global_load_lds((as1_u32p)g, (as3_u32p)l, 16, 0, 0);
}

// ======== shared phase bodies (used by both fused and split kernels) ========

__device__ __forceinline__ void normalize_rows(int row0, int nrows_per, const float* z1,
                                               const float* z2, bf16* zn, float* invn,
                                               float* rowsum) {
  const int wave = threadIdx.x >> 6, lane = threadIdx.x & 63;
  for (int i = 0; i < nrows_per; ++i) {
    const int row = row0 + wave * nrows_per + i;
    f32x4 v = *(const f32x4*)(zrow(z1, z2, row) + lane * 4);
    float ss = v.x * v.x + v.y * v.y + v.z * v.z + v.w * v.w;
#pragma unroll
    for (int off = 1; off < 64; off <<= 1) ss += __shfl_xor(ss, off);
    const float inv = 1.0f / fmaxf(sqrtf(ss), 1e-8f);
    bf16x4 o;
    o.x = (bf16)(v.x * inv); o.y = (bf16)(v.y * inv);
    o.z = (bf16)(v.z * inv); o.w = (bf16)(v.w * inv);
    *(bf16x4*)(zn + (size_t)row * DDIM + lane * 4) = o;
    if (lane == 0) { invn[row] = inv; rowsum[row] = 0.0f; }
  }
}

// circulant symmetric Gram body; ldsb = 2 x 32KB buffers.
// Block (I, chunk): I in [0,64) row-tile of 128; chunk in [0,8) covers d-values
// {4c..4c+3} (+d=32 for chunk7 when I<32). J=(I+d)&63. d=0 tile: row-sums only.
// Off-diag: rows AND cols. Coverage: d in [1,31] once, d=32 once via I<32.
__device__ __forceinline__ void gram_body(unsigned char (*ldsb)[64 * 512], const bf16* zn,
                                          float* rowsum, int bid) {
  const int tid  = threadIdx.x;
  const int wave = tid >> 6, lane = tid & 63;
  const int quad = lane >> 4, l15 = lane & 15;

  const int I      = bid >> 3;
  const int chunk  = bid & 7;
  const int base_d = chunk * 4;
  const int n      = (chunk == 7 && I < 32) ? 10 : 8;  // 64-col LDS-iters
  const int R0     = I * 128 + wave * 32;

  auto cbase = [&](int t) -> int {
    const int d = base_d + (t >> 1);
    const int J = (I + d) & 63;
    return J * 128 + (t & 1) * 64;
  };
  auto issue_dma = [&](int t, int b) {
    const unsigned char* s = (const unsigned char*)(zn + (size_t)cbase(t) * DDIM);
#pragma unroll
    for (int j = 0; j < 8; ++j) {
      const int p = (wave * 8 + j) * 64 + lane;  // 16B-chunk position 0..2047
      const int r = p >> 5;                      // staged col-row 0..63
      const int q = (p & 31) ^ (r & 15);         // swizzle inverse on SOURCE
      load_lds16(s + r * 512 + q * 16, &ldsb[b][(wave * 8 + j) * 1024]);
    }
  };

  // pinned VMEM issue order: [D(0) x8] [A x16] [D(1) x8]
  issue_dma(0, 0);
  __builtin_amdgcn_sched_barrier(0);

  bf16x8 a[2][8];
#pragma unroll
  for (int s = 0; s < 2; ++s) {
    const bf16x8* ap = (const bf16x8*)(zn + (size_t)(R0 + s * 16 + l15) * DDIM);
#pragma unroll
    for (int kk = 0; kk < 8; ++kk) a[s][kk] = ap[kk * 4 + quad];
  }
  __builtin_amdgcn_sched_barrier(0);

  issue_dma(1, 1);
  __builtin_amdgcn_sched_barrier(0);

  float sum[2][4] = {{0.f, 0.f, 0.f, 0.f}, {0.f, 0.f, 0.f, 0.f}};
  const f32x4 zero4 = {0.f, 0.f, 0.f, 0.f};

  for (int t = 0; t < n; ++t) {
    // Counted wait: leaves D(t+1)'s 8 DMAs in flight; last iter drains all.
    if (t == n - 1) asm volatile("s_waitcnt vmcnt(0)" ::: "memory");
    else            asm volatile("s_waitcnt vmcnt(8)" ::: "memory");
    __builtin_amdgcn_s_barrier();        // all waves' DMA for tile t complete
    __builtin_amdgcn_sched_barrier(0);   // no ds_read hoisting above barrier

    const unsigned char* bp = ldsb[t & 1];

    f32x4 acc[2][4];
#pragma unroll
    for (int s = 0; s < 2; ++s)
#pragma unroll
      for (int cs = 0; cs < 4; ++cs) acc[s][cs] = zero4;

    __builtin_amdgcn_s_setprio(1);
#pragma unroll
    for (int kk = 0; kk < 8; ++kk) {
      bf16x8 b[4];
#pragma unroll
      for (int cs = 0; cs < 4; ++cs) {
        const int rb = cs * 16 + l15;                // staged col-row 0..63
        const int sl = (kk * 4 + quad) ^ (rb & 15);  // swizzled chunk slot
        b[cs] = *(const bf16x8*)(bp + rb * 512 + sl * 16);
      }
#pragma unroll
      for (int s = 0; s < 2; ++s)
#pragma unroll
        for (int cs = 0; cs < 4; ++cs)
          acc[s][cs] =
              __builtin_amdgcn_mfma_f32_16x16x32_bf16(a[s][kk], b[cs], acc[s][cs], 0, 0, 0);
    }
    __builtin_amdgcn_s_setprio(0);

    // exp + row accumulation + per-iter col atomics (off-diag only)
    const bool dg = (chunk == 0 && t < 2);  // d==0 diagonal tile
    const int cb = cbase(t);
#pragma unroll
    for (int cs = 0; cs < 4; ++cs) {
      float c = 0.f;
#pragma unroll
      for (int s = 0; s < 2; ++s)
#pragma unroll
        for (int r = 0; r < 4; ++r) {
          const float e = __builtin_amdgcn_exp2f(acc[s][cs][r] * kTwoLog2e);
          sum[s][r] += e;
          c += e;
        }
      if (!dg) {
        c += __shfl_xor(c, 16); c += __shfl_xor(c, 32);
        if (quad == 0) atomicAdd(&rowsum[cb + cs * 16 + l15], c);
      }
    }

    __builtin_amdgcn_s_barrier();        // all waves done READING tile t
    __builtin_amdgcn_sched_barrier(0);
    if (t + 2 < n) {
      issue_dma(t + 2, t & 1);           // overwrite just-freed buffer
      __builtin_amdgcn_sched_barrier(0);
    }
  }

  // row-sums: C/D layout (m89): row = quad*4 + r, col = l15
#pragma unroll
  for (int s = 0; s < 2; ++s)
#pragma unroll
    for (int r = 0; r < 4; ++r) {
      float v = sum[s][r];
      v += __shfl_xor(v, 1); v += __shfl_xor(v, 2);
      v += __shfl_xor(v, 4); v += __shfl_xor(v, 8);
      if (l15 == 0) atomicAdd(&rowsum[R0 + s * 16 + quad * 4 + r], v);
    }
}

__device__ __forceinline__ float finalize_rows(int row0, int nrows_per, const float* z1,
                                               const float* z2, const bf16* zn,
                                               const float* invn, const float* rowsum) {
  const int wave = threadIdx.x >> 6, lane = threadIdx.x & 63;
  float cacc = 0.0f;
  for (int i = 0; i < nrows_per; ++i) {
    const int row = row0 + wave * nrows_per + i;
    const int pr = (row < NHALF) ? row + NHALF : row - NHALF;
    f32x4 a4 = *(const f32x4*)(zrow(z1, z2, row) + lane * 4);
    f32x4 b4 = *(const f32x4*)(zrow(z1, z2, pr) + lane * 4);
    bf16x4 nb = *(const bf16x4*)(zn + (size_t)row * DDIM + lane * 4);
    float pd = a4.x * b4.x + a4.y * b4.y + a4.z * b4.z + a4.w * b4.w;
    float f0 = (float)nb.x, f1 = (float)nb.y, f2 = (float)nb.z, f3 = (float)nb.w;
    float nd = f0 * f0 + f1 * f1 + f2 * f2 + f3 * f3;
#pragma unroll
    for (int off = 1; off < 64; off <<= 1) {
      pd += __shfl_xor(pd, off);
      nd += __shfl_xor(nd, off);
    }
    const float p = 2.0f * pd * invn[row] * invn[pr];              // exact fp32 pair sim
    const float dexp = __builtin_amdgcn_exp2f(kTwoLog2e * nd);     // Gram's diagonal term
    const float lse = __builtin_amdgcn_logf(rowsum[row] - dexp) * kLn2;
    cacc += lse - p;
  }
  return cacc;
}

// ======== fused cooperative kernel ========
__global__ __launch_bounds__(256, 2) void k_fused(const float* __restrict__ z1,
                                                  const float* __restrict__ z2,
                                                  bf16* __restrict__ zn,
                                                  float* __restrict__ invn,
                                                  float* __restrict__ rowsum,
                                                  float* __restrict__ out) {
  __shared__ __align__(16) unsigned char ldsb[2][64 * 512];  // 64KB -> 2 blocks/CU
  const int tid = threadIdx.x;

  normalize_rows(blockIdx.x * 16, 4, z1, z2, zn, invn, rowsum);
  if (blockIdx.x == 0 && tid == 0) out[0] = 0.0f;

  cg::this_grid().sync();  // zn/invn/rowsum-zero visible device-wide

  gram_body(ldsb, zn, rowsum, blockIdx.x);

  cg::this_grid().sync();  // all rowsum atomics visible device-wide

  const float cacc = finalize_rows(blockIdx.x * 16, 4, z1, z2, zn, invn, rowsum);
  float* wsum = (float*)&ldsb[0][0];  // LDS reuse; phase2 done (grid.sync passed)
  const int wave = tid >> 6, lane = tid & 63;
  if (lane == 0) wsum[wave] = cacc;
  __syncthreads();
  if (tid == 0)
    atomicAdd(out, (wsum[0] + wsum[1] + wsum[2] + wsum[3]) * (1.0f / (float)NROWS));
}

// ======== fallback split kernels (proven v5 path) ========
__global__ void k_normalize(const float* __restrict__ z1, const float* __restrict__ z2,
                            bf16* __restrict__ zn, float* __restrict__ invn,
                            float* __restrict__ rowsum, float* __restrict__ out) {
  normalize_rows(blockIdx.x * 4, 1, z1, z2, zn, invn, rowsum);
  if (blockIdx.x == 0 && threadIdx.x == 0) out[0] = 0.0f;
}

__global__ __launch_bounds__(256, 2) void k_gram(const bf16* __restrict__ zn,
                                                 float* __restrict__ rowsum) {
  __shared__ __align__(16) unsigned char ldsb[2][64 * 512];
  gram_body(ldsb, zn, rowsum, blockIdx.x);
}

__global__ void k_finalize(const float* __restrict__ z1, const float* __restrict__ z2,
                           const bf16* __restrict__ zn, const float* __restrict__ invn,
                           const float* __restrict__ rowsum, float* __restrict__ out) {
  const float cacc = finalize_rows(blockIdx.x * 4, 1, z1, z2, zn, invn, rowsum);
  __shared__ float wsum[4];
  const int wave = threadIdx.x >> 6, lane = threadIdx.x & 63;
  if (lane == 0) wsum[wave] = cacc;
  __syncthreads();
  if (threadIdx.x == 0)
    atomicAdd(out, (wsum[0] + wsum[1] + wsum[2] + wsum[3]) * (1.0f / (float)NROWS));
}

extern "C" void kernel_launch(void* const* d_in, const int* in_sizes, int n_in,
                              void* d_out, int out_size, void* d_ws, size_t ws_size,
                              hipStream_t stream) {
  const float* z1 = (const float*)d_in[0];
  const float* z2 = (const float*)d_in[1];
  unsigned char* ws = (unsigned char*)d_ws;

  // ws layout: zn bf16 [8192*256] (4 MB) | invn f32[8192] | rowsum f32[8192]
  bf16* zn = (bf16*)ws;
  float* invn = (float*)(ws + (size_t)NROWS * DDIM * sizeof(bf16));
  float* rowsum = invn + NROWS;
  float* out = (float*)d_out;

  void* args[] = {(void*)&z1, (void*)&z2, (void*)&zn, (void*)&invn, (void*)&rowsum, (void*)&out};
  hipError_t err =
      hipLaunchCooperativeKernel((const void*)k_fused, dim3(NBLK), dim3(256), args, 0, stream);
  if (err != hipSuccess) {
    // cooperative launch rejected (capture-unsupported / too-large): proven split path
    hipLaunchKernelGGL(k_normalize, dim3(NROWS / 4), dim3(256), 0, stream, z1, z2, zn, invn,
                       rowsum, out);
    hipLaunchKernelGGL(k_gram, dim3(NBLK), dim3(256), 0, stream, zn, rowsum);
    hipLaunchKernelGGL(k_finalize, dim3(NROWS / 4), dim3(256), 0, stream, z1, z2, zn, invn,
                       rowsum, out);
  }
}

// Round 8
// 118.188 us; speedup vs baseline: 1.8461x; 1.8461x over previous
//
#include <hip/hip_runtime.h>
#include <hip/hip_bf16.h>

// NT-Xent loss, N=4096, D=256, fp32 inputs, fp32 scalar output.
// loss = mean_i [ log( sum_{j != i} exp(2*cos(zn_i, zn_j)) ) - 2*cos(zn_i, zn_pair(i)) ]
//
// v8: 3-kernel split path (r7: cooperative grid.sync cost ~100us -> refuted).
// k1: normalize -> bf16 zn, invn, zero rowsum/out
// k2: circulant symmetric Gram exp-rowsums. KEY FIX vs r1-r5: global atomics
//     are REMOVED from the counted-vmcnt pipeline (atomics count in vmcnt, so
//     per-iter col atomicAdds chained every vmcnt(8) wait to contended L2
//     atomic retirement -- the invariant 40-48us across all five variants).
//     Col partials now go to LDS scratch (lgkmcnt domain), single cross-wave
//     flush of global atomics AFTER the final vmcnt(0). 4x fewer col atomics,
//     all off the critical path.
// k3: per-row contrib + block reduce -> atomicAdd(out)

#define NROWS 8192
#define NHALF 4096
#define DDIM  256
#define NBLK  512

typedef __bf16 bf16;
typedef __bf16 bf16x4 __attribute__((ext_vector_type(4)));
typedef __bf16 bf16x8 __attribute__((ext_vector_type(8)));
typedef float  f32x4  __attribute__((ext_vector_type(4)));

__constant__ const float kTwoLog2e = 2.8853900817779268f;  // 2*log2(e): exp(2x)=exp2(kTwoLog2e*x)
__constant__ const float kLn2      = 0.6931471805599453f;

__device__ __forceinline__ const float* zrow(const float* z1, const float* z2, int r) {
  return (r < NHALF) ? (z1 + (size_t)r * DDIM) : (z2 + (size_t)(r - NHALF) * DDIM);
}

typedef const __attribute__((address_space(1))) unsigned int* as1_u32p;
typedef __attribute__((address_space(3))) unsigned int* as3_u32p;

__device__ __forceinline__ void load_lds16(const void* g, void* l) {
  __builtin_amdgcn_global_load_lds((as1_u32p)g, (as3_u32p)l, 16, 0, 0);
}

// ---------------- k1: normalize ----------------
__global__ void k_normalize(const float* __restrict__ z1, const float* __restrict__ z2,
                            bf16* __restrict__ zn, float* __restrict__ invn,
                            float* __restrict__ rowsum, float* __restrict__ out) {
  const int wave = threadIdx.x >> 6, lane = threadIdx.x & 63;
  const int row = blockIdx.x * 4 + wave;
  f32x4 v = *(const f32x4*)(zrow(z1, z2, row) + lane * 4);
  float ss = v.x * v.x + v.y * v.y + v.z * v.z + v.w * v.w;
#pragma unroll
  for (int off = 1; off < 64; off <<= 1) ss += __shfl_xor(ss, off);
  const float inv = 1.0f / fmaxf(sqrtf(ss), 1e-8f);
  bf16x4 o;
  o.x = (bf16)(v.x * inv); o.y = (bf16)(v.y * inv);
  o.z = (bf16)(v.z * inv); o.w = (bf16)(v.w * inv);
  *(bf16x4*)(zn + (size_t)row * DDIM + lane * 4) = o;
  if (lane == 0) { invn[row] = inv; rowsum[row] = 0.0f; }
  if (blockIdx.x == 0 && threadIdx.x == 0) out[0] = 0.0f;
}

// ---------------- k2: circulant symmetric Gram ----------------
// Block (I, chunk): I in [0,64) row-tile of 128; chunk in [0,8) covers d-values
// {4c..4c+3} (+d=32 for chunk7 when I<32). J=(I+d)&63; 64-col LDS-iters, n=8 or
// 10. d=0 tile: row-sums only. Off-diag: rows AND cols (col-sum = transposed
// tile's row-sum). Coverage: d in [1,31] once, d=32 once via I<32. Rolling
// 2-buffer DMA, counted vmcnt(8); loop VMEM = DMA ONLY (no atomics).
__global__ __launch_bounds__(256, 2) void k_gram(const bf16* __restrict__ zn,
                                                 float* __restrict__ rowsum) {
  __shared__ __align__(16) unsigned char ldsb[2][64 * 512];  // 64KB staging
  __shared__ float cpart[4][640];                            // 10KB col partials
  const int tid  = threadIdx.x;
  const int wave = tid >> 6, lane = tid & 63;
  const int quad = lane >> 4, l15 = lane & 15;

  const int I      = blockIdx.x >> 3;
  const int chunk  = blockIdx.x & 7;
  const int base_d = chunk * 4;
  const int n      = (chunk == 7 && I < 32) ? 10 : 8;  // 64-col LDS-iters
  const int R0     = I * 128 + wave * 32;

  auto cbase = [&](int t) -> int {
    const int d = base_d + (t >> 1);
    const int J = (I + d) & 63;
    return J * 128 + (t & 1) * 64;
  };
  auto issue_dma = [&](int t, int b) {
    const unsigned char* s = (const unsigned char*)(zn + (size_t)cbase(t) * DDIM);
#pragma unroll
    for (int j = 0; j < 8; ++j) {
      const int p = (wave * 8 + j) * 64 + lane;  // 16B-chunk position 0..2047
      const int r = p >> 5;                      // staged col-row 0..63
      const int q = (p & 31) ^ (r & 15);         // swizzle inverse on SOURCE
      load_lds16(s + r * 512 + q * 16, &ldsb[b][(wave * 8 + j) * 1024]);
    }
  };

  // pinned VMEM issue order: [D(0) x8] [A x16] [D(1) x8]
  issue_dma(0, 0);
  __builtin_amdgcn_sched_barrier(0);

  bf16x8 a[2][8];
#pragma unroll
  for (int s = 0; s < 2; ++s) {
    const bf16x8* ap = (const bf16x8*)(zn + (size_t)(R0 + s * 16 + l15) * DDIM);
#pragma unroll
    for (int kk = 0; kk < 8; ++kk) a[s][kk] = ap[kk * 4 + quad];
  }
  __builtin_amdgcn_sched_barrier(0);

  issue_dma(1, 1);
  __builtin_amdgcn_sched_barrier(0);

  float sum[2][4] = {{0.f, 0.f, 0.f, 0.f}, {0.f, 0.f, 0.f, 0.f}};
  const f32x4 zero4 = {0.f, 0.f, 0.f, 0.f};

  for (int t = 0; t < n; ++t) {
    // Counted wait: only the 8 DMAs of D(t+1) remain in flight (loop VMEM is
    // DMA-only now); last iter drains all.
    if (t == n - 1) asm volatile("s_waitcnt vmcnt(0)" ::: "memory");
    else            asm volatile("s_waitcnt vmcnt(8)" ::: "memory");
    __builtin_amdgcn_s_barrier();        // all waves' DMA for tile t complete
    __builtin_amdgcn_sched_barrier(0);   // no ds_read hoisting above barrier

    const unsigned char* bp = ldsb[t & 1];

    f32x4 acc[2][4];
#pragma unroll
    for (int s = 0; s < 2; ++s)
#pragma unroll
      for (int cs = 0; cs < 4; ++cs) acc[s][cs] = zero4;

    __builtin_amdgcn_s_setprio(1);
#pragma unroll
    for (int kk = 0; kk < 8; ++kk) {
      bf16x8 b[4];
#pragma unroll
      for (int cs = 0; cs < 4; ++cs) {
        const int rb = cs * 16 + l15;                // staged col-row 0..63
        const int sl = (kk * 4 + quad) ^ (rb & 15);  // swizzled chunk slot
        b[cs] = *(const bf16x8*)(bp + rb * 512 + sl * 16);
      }
#pragma unroll
      for (int s = 0; s < 2; ++s)
#pragma unroll
        for (int cs = 0; cs < 4; ++cs)
          acc[s][cs] =
              __builtin_amdgcn_mfma_f32_16x16x32_bf16(a[s][kk], b[cs], acc[s][cs], 0, 0, 0);
    }
    __builtin_amdgcn_s_setprio(0);

    // exp + row accumulation; col partials -> LDS (lgkmcnt domain, NOT vmcnt)
    const bool dg = (chunk == 0 && t < 2);  // d==0 diagonal tile
#pragma unroll
    for (int cs = 0; cs < 4; ++cs) {
      float c = 0.f;
#pragma unroll
      for (int s = 0; s < 2; ++s)
#pragma unroll
        for (int r = 0; r < 4; ++r) {
          const float e = __builtin_amdgcn_exp2f(acc[s][cs][r] * kTwoLog2e);
          sum[s][r] += e;
          c += e;
        }
      c += __shfl_xor(c, 16); c += __shfl_xor(c, 32);   // wave col-sum, all lanes
      if (!dg && quad == 0) cpart[wave][t * 64 + cs * 16 + l15] = c;
    }

    __builtin_amdgcn_s_barrier();        // all waves done READING tile t
    __builtin_amdgcn_sched_barrier(0);
    if (t + 2 < n) {
      issue_dma(t + 2, t & 1);           // overwrite just-freed buffer
      __builtin_amdgcn_sched_barrier(0);
    }
  }

  // ---- row-sums (wave-exclusive rows): C/D layout (m89): row=quad*4+r, col=l15 ----
#pragma unroll
  for (int s = 0; s < 2; ++s)
#pragma unroll
    for (int r = 0; r < 4; ++r) {
      float v = sum[s][r];
      v += __shfl_xor(v, 1); v += __shfl_xor(v, 2);
      v += __shfl_xor(v, 4); v += __shfl_xor(v, 8);
      if (l15 == 0) atomicAdd(&rowsum[R0 + s * 16 + quad * 4 + r], v);
    }

  // ---- col flush: cross-wave combine in LDS, ONE global atomic per col ----
  __syncthreads();  // cpart visible; pipeline fully drained (off critical path)
  for (int idx = tid; idx < 64 * n; idx += 256) {
    const int t = idx >> 6;
    if (chunk == 0 && t < 2) continue;  // diagonal tile: no col contribution
    const float v = cpart[0][idx] + cpart[1][idx] + cpart[2][idx] + cpart[3][idx];
    atomicAdd(&rowsum[cbase(t) + (idx & 63)], v);
  }
}

// ---------------- k3: per-row contribution + fused reduce ----------------
__global__ void k_finalize(const float* __restrict__ z1, const float* __restrict__ z2,
                           const bf16* __restrict__ zn, const float* __restrict__ invn,
                           const float* __restrict__ rowsum, float* __restrict__ out) {
  const int wave = threadIdx.x >> 6, lane = threadIdx.x & 63;
  const int row = blockIdx.x * 4 + wave;
  const int pr = (row < NHALF) ? row + NHALF : row - NHALF;

  f32x4 a4 = *(const f32x4*)(zrow(z1, z2, row) + lane * 4);
  f32x4 b4 = *(const f32x4*)(zrow(z1, z2, pr) + lane * 4);
  bf16x4 nb = *(const bf16x4*)(zn + (size_t)row * DDIM + lane * 4);

  float pd = a4.x * b4.x + a4.y * b4.y + a4.z * b4.z + a4.w * b4.w;
  float f0 = (float)nb.x, f1 = (float)nb.y, f2 = (float)nb.z, f3 = (float)nb.w;
  float nd = f0 * f0 + f1 * f1 + f2 * f2 + f3 * f3;
#pragma unroll
  for (int off = 1; off < 64; off <<= 1) {
    pd += __shfl_xor(pd, off);
    nd += __shfl_xor(nd, off);
  }
  __shared__ float wsum[4];
  if (lane == 0) {
    const float p = 2.0f * pd * invn[row] * invn[pr];              // exact fp32 pair sim
    const float dexp = __builtin_amdgcn_exp2f(kTwoLog2e * nd);     // Gram's diagonal term
    const float lse = __builtin_amdgcn_logf(rowsum[row] - dexp) * kLn2;
    wsum[wave] = lse - p;
  }
  __syncthreads();
  if (threadIdx.x == 0)
    atomicAdd(out, (wsum[0] + wsum[1] + wsum[2] + wsum[3]) * (1.0f / (float)NROWS));
}

extern "C" void kernel_launch(void* const* d_in, const int* in_sizes, int n_in,
                              void* d_out, int out_size, void* d_ws, size_t ws_size,
                              hipStream_t stream) {
  const float* z1 = (const float*)d_in[0];
  const float* z2 = (const float*)d_in[1];
  unsigned char* ws = (unsigned char*)d_ws;

  // ws layout: zn bf16 [8192*256] (4 MB) | invn f32[8192] | rowsum f32[8192]
  bf16* zn = (bf16*)ws;
  float* invn = (float*)(ws + (size_t)NROWS * DDIM * sizeof(bf16));
  float* rowsum = invn + NROWS;
  float* out = (float*)d_out;

  hipLaunchKernelGGL(k_normalize, dim3(NROWS / 4), dim3(256), 0, stream, z1, z2, zn, invn, rowsum,
                     out);
  hipLaunchKernelGGL(k_gram, dim3(NBLK), dim3(256), 0, stream, zn, rowsum);
  hipLaunchKernelGGL(k_finalize, dim3(NROWS / 4), dim3(256), 0, stream, z1, z2, zn, invn, rowsum,
                     out);
}